// Round 6
// baseline (256.988 us; speedup 1.0000x reference)
//
#include <hip/hip_runtime.h>
#include <hip/hip_fp16.h>
#include <stdint.h>

#define LOG2_HASHMAP_SIZE 19
#define HASHMAP_SIZE (1u << LOG2_HASHMAP_SIZE)
#define HASHMAP_MASK (HASHMAP_SIZE - 1u)
#define N_LEVELS 4

// Level 0: res=30 -> 31 vertices/axis. Dense grid fits in LDS as half2.
#define R0 31
#define DENSE0_N (R0 * R0 * R0)        // 29791
#define DENSE0_BYTES (DENSE0_N * 4)    // 119164 B < 160 KiB

// Level 1: res=80 -> 81 vertices/axis. Dense z-pair grid in global mem:
// 2 parity copies of overlapping (z, z+1) uint2 entries (2x half2 = 8B).
// One 8B load returns both z-corners -> 4 transactions per point, and the
// structure is ~4.1 MB, i.e. per-XCD-L2-resident (the 8.7 MB quad was not).
#define R1 81
#define D1_N (R1 * R1 * R1)            // 531441 scalar vertices (half2 each)
#define ZQ 41                          // z-pair slots per axis
#define ZP_N (2 * R1 * R1 * ZQ)        // 538002 pair entries
#define ZP_BYTES ((size_t)ZP_N * 8)    // 4,304,016 B

// native vector types usable with __builtin_nontemporal_*
typedef float v4f __attribute__((ext_vector_type(4)));
typedef float v2f __attribute__((ext_vector_type(2)));

__device__ __forceinline__ uint32_t hash3(uint32_t ix, uint32_t iy, uint32_t iz) {
    return (ix ^ (iy * 11614769u) ^ (iz * 2654435761u)) & HASHMAP_MASK;
}

__device__ __forceinline__ float2 h2f(uint32_t p) {
    return __half22float2(*(const __half2*)&p);
}
__device__ __forceinline__ uint32_t f2h(float a, float b) {
    const __half2 p = __floats2half2_rn(a, b);
    return *(const uint32_t*)&p;
}

// ---------------- fp32 path (fallback only) ----------------
__device__ __forceinline__ float2 level_embed_p(float px, float py, float pz,
                                                const float* __restrict__ tables,
                                                int li, float r)
{
    const uint32_t P1 = 11614769u;
    const uint32_t P2 = 2654435761u;

    const float sx = px * r, sy = py * r, sz = pz * r;
    const float bx = floorf(sx), by = floorf(sy), bz = floorf(sz);
    const float tx = sx - bx, ty = sy - by, tz = sz - bz;
    const float ux = 1.0f - tx, uy = 1.0f - ty, uz = 1.0f - tz;

    const uint32_t ix = (uint32_t)(int)bx;
    const uint32_t iy = (uint32_t)(int)by;
    const uint32_t iz = (uint32_t)(int)bz;

    const uint32_t hy0 = iy * P1, hy1 = (iy + 1u) * P1;
    const uint32_t hz0 = iz * P2, hz1 = (iz + 1u) * P2;

    uint32_t S[4];
    float W[4];
    S[0] = hy0 ^ hz0;  W[0] = uy * uz;
    S[1] = hy0 ^ hz1;  W[1] = uy * tz;
    S[2] = hy1 ^ hz0;  W[2] = ty * uz;
    S[3] = hy1 ^ hz1;  W[3] = ty * tz;

    const float* tab = tables + (size_t)li * HASHMAP_SIZE * 2;
    const float2* __restrict__ tab2 = (const float2*)tab;

    float f0 = 0.0f, f1 = 0.0f;
    #pragma unroll
    for (int c = 0; c < 4; ++c) {
        const uint32_t h0 = (ix ^ S[c]) & HASHMAP_MASK;
        const uint32_t h1 = ((ix + 1u) ^ S[c]) & HASHMAP_MASK;
        const float2 e0 = tab2[h0];
        const float2 e1 = tab2[h1];
        f0 += W[c] * (ux * e0.x + tx * e1.x);
        f1 += W[c] * (ux * e0.y + tx * e1.y);
    }
    return make_float2(f0, f1);
}

// ---------------- fp16 hash gather (divergent even/odd — measured fastest:
// avg 6 L2-hit transactions per point-level = the HW ceiling unit) ----------
__device__ __forceinline__ float2 level_embed_h16(float px, float py, float pz,
                                                  const uint32_t* __restrict__ t16,
                                                  float r)
{
    const uint32_t P1 = 11614769u;
    const uint32_t P2 = 2654435761u;

    const float sx = px * r, sy = py * r, sz = pz * r;
    const float bx = floorf(sx), by = floorf(sy), bz = floorf(sz);
    const float tx = sx - bx, ty = sy - by, tz = sz - bz;
    const float ux = 1.0f - tx, uy = 1.0f - ty, uz = 1.0f - tz;

    const uint32_t ix = (uint32_t)(int)bx;
    const uint32_t iy = (uint32_t)(int)by;
    const uint32_t iz = (uint32_t)(int)bz;

    const uint32_t hy0 = iy * P1, hy1 = (iy + 1u) * P1;
    const uint32_t hz0 = iz * P2, hz1 = (iz + 1u) * P2;

    uint32_t S[4];
    float W[4];
    S[0] = hy0 ^ hz0;  W[0] = uy * uz;
    S[1] = hy0 ^ hz1;  W[1] = uy * tz;
    S[2] = hy1 ^ hz0;  W[2] = ty * uz;
    S[3] = hy1 ^ hz1;  W[3] = ty * tz;

    float f0 = 0.0f, f1 = 0.0f;
    if ((ix & 1u) == 0u) {
        // even ix: one aligned 8B load covers both x-corners
        #pragma unroll
        for (int c = 0; c < 4; ++c) {
            const uint32_t h0 = (ix ^ S[c]) & HASHMAP_MASK;
            const uint2 v = ((const uint2*)t16)[h0 >> 1];
            const uint32_t p0 = (h0 & 1u) ? v.y : v.x;
            const uint32_t p1 = (h0 & 1u) ? v.x : v.y;
            const float2 e0 = h2f(p0);
            const float2 e1 = h2f(p1);
            f0 += W[c] * (ux * e0.x + tx * e1.x);
            f1 += W[c] * (ux * e0.y + tx * e1.y);
        }
    } else {
        #pragma unroll
        for (int c = 0; c < 4; ++c) {
            const uint32_t h0 = (ix ^ S[c]) & HASHMAP_MASK;
            const uint32_t h1 = ((ix + 1u) ^ S[c]) & HASHMAP_MASK;
            const float2 e0 = h2f(t16[h0]);
            const float2 e1 = h2f(t16[h1]);
            f0 += W[c] * (ux * e0.x + tx * e1.x);
            f1 += W[c] * (ux * e0.y + tx * e1.y);
        }
    }
    return make_float2(f0, f1);
}

// ---------------- setup kernels ----------------
// Pack levels 2,3 tables to fp16 (half2 per entry).
__global__ __launch_bounds__(256) void convert_fp16(
    const float* __restrict__ tables, uint32_t* __restrict__ t16)
{
    const int i = blockIdx.x * blockDim.x + threadIdx.x;
    if (i >= 2 * (int)HASHMAP_SIZE) return;
    const float2 e = ((const float2*)tables)[2 * HASHMAP_SIZE + i];  // levels 2,3
    t16[i] = f2h(e.x, e.y);
}

// Level-0 dense vertex grid as half2 (for LDS staging in final).
__global__ __launch_bounds__(256) void build_dense0(
    const float* __restrict__ tables, uint32_t* __restrict__ dense0)
{
    const int v = blockIdx.x * blockDim.x + threadIdx.x;
    if (v >= DENSE0_N) return;
    const int vx = v / (R0 * R0);
    const int rem = v - vx * (R0 * R0);
    const int vy = rem / R0;
    const int vz = rem - vy * R0;
    const uint32_t h = hash3((uint32_t)vx, (uint32_t)vy, (uint32_t)vz);
    const float2 e = ((const float2*)tables)[h];   // level-0 table at offset 0
    dense0[v] = f2h(e.x, e.y);
}

// Level-1 scalar dense grid (hash applied once per vertex: 531K gathers).
__global__ __launch_bounds__(256) void build_dense1(
    const float* __restrict__ tables, uint32_t* __restrict__ d1)
{
    const int v = blockIdx.x * blockDim.x + threadIdx.x;
    if (v >= D1_N) return;
    const int vx = v / (R1 * R1);
    const int rem = v - vx * (R1 * R1);
    const int vy = rem / R1;
    const int vz = rem - vy * R1;
    const uint32_t h = hash3((uint32_t)vx, (uint32_t)vy, (uint32_t)vz);
    const float2 e = ((const float2*)tables)[HASHMAP_SIZE + h];   // level 1
    d1[v] = f2h(e.x, e.y);
}

// Expand scalar grid into 2 parity copies of overlapping z-pairs.
// Entry (p, x, y, zq) = { v[z0], v[z0+1] } with z0 = 2*zq + p (clamped).
__global__ __launch_bounds__(256) void expand_zpair(
    const uint32_t* __restrict__ d1, uint2* __restrict__ zp)
{
    const int t = blockIdx.x * blockDim.x + threadIdx.x;
    if (t >= ZP_N) return;
    const int per_copy = R1 * R1 * ZQ;
    const int p = t / per_copy;
    int rem = t - p * per_copy;
    const int vx = rem / (R1 * ZQ);
    rem -= vx * (R1 * ZQ);
    const int vy = rem / ZQ;
    const int zq = rem - vy * ZQ;
    int z0 = 2 * zq + p;
    int z1 = z0 + 1;
    z0 = min(z0, R1 - 1);   // clamp: padded slots never used by valid iz
    z1 = min(z1, R1 - 1);
    const uint32_t* base = d1 + ((size_t)vx * R1 + vy) * R1;
    uint2 q;
    q.x = base[z0];
    q.y = base[z1];
    zp[t] = q;
}

// ---------------- pass kernels ----------------
// Level 1 via z-pair grid: exactly 4 transactions per point, L2-resident.
__global__ __launch_bounds__(256) void pass1_zpair(
    const float* __restrict__ x, const uint2* __restrict__ zp,
    uint32_t* __restrict__ ws, int n)
{
    const int i = blockIdx.x * blockDim.x + threadIdx.x;
    if (i >= n) return;
    const float px = __builtin_nontemporal_load(x + 3 * (size_t)i + 0);
    const float py = __builtin_nontemporal_load(x + 3 * (size_t)i + 1);
    const float pz = __builtin_nontemporal_load(x + 3 * (size_t)i + 2);

    const float sx = px * 80.0f, sy = py * 80.0f, sz = pz * 80.0f;
    const float bx = floorf(sx), by = floorf(sy), bz = floorf(sz);
    const float tx = sx - bx, ty = sy - by, tz = sz - bz;
    const float ux = 1.0f - tx, uy = 1.0f - ty, uz = 1.0f - tz;
    const int ix = (int)bx, iy = (int)by, iz = (int)bz;

    const int p  = iz & 1;
    const int zq = iz >> 1;
    const size_t base00 = (((size_t)p * R1 + ix) * R1 + iy) * ZQ + zq;
    const uint2 q00 = zp[base00];               // (x0, y0)
    const uint2 q01 = zp[base00 + ZQ];          // (x0, y1)
    const uint2 q10 = zp[base00 + (size_t)R1 * ZQ];        // (x1, y0)
    const uint2 q11 = zp[base00 + (size_t)R1 * ZQ + ZQ];   // (x1, y1)

    const float2 a00 = h2f(q00.x), a00z = h2f(q00.y);
    const float2 a01 = h2f(q01.x), a01z = h2f(q01.y);
    const float2 a10 = h2f(q10.x), a10z = h2f(q10.y);
    const float2 a11 = h2f(q11.x), a11z = h2f(q11.y);

    // z-lerp then bilinear (x,y)
    const float w00 = ux * uy, w01 = ux * ty, w10 = tx * uy, w11 = tx * ty;
    const float f0 = w00 * (uz * a00.x + tz * a00z.x)
                   + w01 * (uz * a01.x + tz * a01z.x)
                   + w10 * (uz * a10.x + tz * a10z.x)
                   + w11 * (uz * a11.x + tz * a11z.x);
    const float f1 = w00 * (uz * a00.y + tz * a00z.y)
                   + w01 * (uz * a01.y + tz * a01z.y)
                   + w10 * (uz * a10.y + tz * a10z.y)
                   + w11 * (uz * a11.y + tz * a11z.y);

    __builtin_nontemporal_store(f2h(f0, f1), ws + i);
}

// Level 2 via fp16 hash table (2 MB, L2-resident).
__global__ __launch_bounds__(256) void pass2_hash(
    const float* __restrict__ x, const uint32_t* __restrict__ t16,
    uint32_t* __restrict__ ws, int n)
{
    const int i = blockIdx.x * blockDim.x + threadIdx.x;
    if (i >= n) return;
    const float px = __builtin_nontemporal_load(x + 3 * (size_t)i + 0);
    const float py = __builtin_nontemporal_load(x + 3 * (size_t)i + 1);
    const float pz = __builtin_nontemporal_load(x + 3 * (size_t)i + 2);
    const float2 e = level_embed_h16(px, py, pz, t16, 210.0f);
    __builtin_nontemporal_store(f2h(e.x, e.y), ws + i);
}

extern __shared__ uint32_t s_dense[];   // DENSE0_N packed half2

// Final: level 3 (fp16 hash gather) + level 0 (LDS) + combine ws1/ws2.
__global__ __launch_bounds__(1024) void final16_kernel(
    const float* __restrict__ x, const uint32_t* __restrict__ t16_l3,
    const uint32_t* __restrict__ dense0,
    const uint32_t* __restrict__ ws1, const uint32_t* __restrict__ ws2,
    float* __restrict__ out, int n)
{
    for (int i = threadIdx.x; i < DENSE0_N; i += 1024)
        s_dense[i] = dense0[i];
    __syncthreads();

    const size_t stride = (size_t)gridDim.x * 1024;
    for (size_t i = (size_t)blockIdx.x * 1024 + threadIdx.x; i < (size_t)n; i += stride) {
        const float px = __builtin_nontemporal_load(x + 3 * i + 0);
        const float py = __builtin_nontemporal_load(x + 3 * i + 1);
        const float pz = __builtin_nontemporal_load(x + 3 * i + 2);

        // level 3: global fp16 gathers (long latency; issue first)
        const float2 e3 = level_embed_h16(px, py, pz, t16_l3, 512.0f);

        // level 0 from LDS dense grid
        const float sx = px * 30.0f, sy = py * 30.0f, sz = pz * 30.0f;
        const float bx = floorf(sx), by = floorf(sy), bz = floorf(sz);
        const float tx = sx - bx, ty = sy - by, tz = sz - bz;
        const float uxv = 1.0f - tx, uyv = 1.0f - ty, uzv = 1.0f - tz;
        const int ix = (int)bx, iy = (int)by, iz = (int)bz;
        const int lin = (ix * R0 + iy) * R0 + iz;

        float f0 = 0.0f, f1 = 0.0f;
        #pragma unroll
        for (int dx = 0; dx < 2; ++dx) {
            const float wx = dx ? tx : uxv;
            #pragma unroll
            for (int dy = 0; dy < 2; ++dy) {
                const float wxy = wx * (dy ? ty : uyv);
                const int base = lin + (dx * R0 + dy) * R0;   // z-corners adjacent
                const float2 c0 = h2f(s_dense[base]);
                const float2 c1 = h2f(s_dense[base + 1]);
                f0 += wxy * (uzv * c0.x + tz * c1.x);
                f1 += wxy * (uzv * c0.y + tz * c1.y);
            }
        }

        const float2 e1 = h2f(__builtin_nontemporal_load(ws1 + i));
        const float2 e2 = h2f(__builtin_nontemporal_load(ws2 + i));

        v4f* op = (v4f*)(out + 8 * i);
        v4f lo = {f0, f1, e1.x, e1.y};
        v4f hi = {e2.x, e2.y, e3.x, e3.y};
        __builtin_nontemporal_store(lo, op);
        __builtin_nontemporal_store(hi, op + 1);
    }
}

// Fallback (ws too small / attribute failure): fp32 per-level pass into out.
__global__ __launch_bounds__(256) void pass_direct_kernel(
    const float* __restrict__ x, const float* __restrict__ tables,
    float* __restrict__ out, int li, float r, int n)
{
    const int i = blockIdx.x * blockDim.x + threadIdx.x;
    if (i >= n) return;
    const float px = x[3 * (size_t)i + 0];
    const float py = x[3 * (size_t)i + 1];
    const float pz = x[3 * (size_t)i + 2];
    const float2 e = level_embed_p(px, py, pz, tables, li, r);
    float2* op = (float2*)(out + 8 * (size_t)i + 2 * li);
    *op = e;
}

extern "C" void kernel_launch(void* const* d_in, const int* in_sizes, int n_in,
                              void* d_out, int out_size, void* d_ws, size_t ws_size,
                              hipStream_t stream) {
    const float* x = (const float*)d_in[0];        // [N, 3]
    const float* tables = (const float*)d_in[1];   // [4, 2^19, 2]
    float* out = (float*)d_out;                    // [N, 8]
    const int n = in_sizes[0] / 3;

    // ws layout (bytes):
    //   [0, 4MB)        : t16 for levels 2,3 (2 MB each)
    //   [+ZP_BYTES)     : level-1 z-pair grid (4.1 MB)
    //   [+D1_N*4)       : level-1 scalar dense grid (2.1 MB, build temp)
    //   [+DENSE0_BYTES) : level-0 dense grid
    //   [+4n)           : ws1 (half2[n])
    //   [+4n)           : ws2 (half2[n])
    const size_t t16_bytes = 2 * (size_t)HASHMAP_SIZE * 4;
    const size_t off_zp    = t16_bytes;
    const size_t off_d1    = off_zp + ZP_BYTES;
    const size_t off_d0    = off_d1 + (size_t)D1_N * 4;
    const size_t off_ws1   = off_d0 + DENSE0_BYTES;
    const size_t off_ws2   = off_ws1 + (size_t)n * 4;
    const size_t ws_needed = off_ws2 + (size_t)n * 4;

    bool fused_ok = (ws_size >= ws_needed);
    if (fused_ok) {
        static int attr_ok = -1;
        if (attr_ok < 0) {
            attr_ok = (hipFuncSetAttribute(
                           reinterpret_cast<const void*>(final16_kernel),
                           hipFuncAttributeMaxDynamicSharedMemorySize,
                           DENSE0_BYTES) == hipSuccess) ? 1 : 0;
        }
        fused_ok = (attr_ok == 1);
    }

    if (fused_ok) {
        char* wsb = (char*)d_ws;
        uint32_t* t16    = (uint32_t*)wsb;
        uint2*    zp     = (uint2*)(wsb + off_zp);
        uint32_t* d1     = (uint32_t*)(wsb + off_d1);
        uint32_t* dense0 = (uint32_t*)(wsb + off_d0);
        uint32_t* ws1    = (uint32_t*)(wsb + off_ws1);
        uint32_t* ws2    = (uint32_t*)(wsb + off_ws2);

        convert_fp16<<<(2 * HASHMAP_SIZE + 255) / 256, 256, 0, stream>>>(tables, t16);
        build_dense0<<<(DENSE0_N + 255) / 256, 256, 0, stream>>>(tables, dense0);
        build_dense1<<<(D1_N + 255) / 256, 256, 0, stream>>>(tables, d1);
        expand_zpair<<<(ZP_N + 255) / 256, 256, 0, stream>>>(d1, zp);

        const int block = 256;
        const int grid = (n + block - 1) / block;
        pass1_zpair<<<grid, block, 0, stream>>>(x, zp, ws1, n);
        pass2_hash<<<grid, block, 0, stream>>>(x, t16, ws2, n);
        final16_kernel<<<256, 1024, DENSE0_BYTES, stream>>>(
            x, t16 + HASHMAP_SIZE, dense0, ws1, ws2, out, n);
    } else {
        const float res[N_LEVELS] = {30.0f, 80.0f, 210.0f, 512.0f};
        const int block = 256;
        const int grid = (n + block - 1) / block;
        for (int li = 0; li < N_LEVELS; ++li) {
            pass_direct_kernel<<<grid, block, 0, stream>>>(
                x, tables, out, li, res[li], n);
        }
    }
}

// Round 7
// 239.362 us; speedup vs baseline: 1.0736x; 1.0736x over previous
//
#include <hip/hip_runtime.h>
#include <hip/hip_fp16.h>
#include <stdint.h>

#define LOG2_HASHMAP_SIZE 19
#define HASHMAP_SIZE (1u << LOG2_HASHMAP_SIZE)
#define HASHMAP_MASK (HASHMAP_SIZE - 1u)
#define N_LEVELS 4

// Level 0: res=30 -> 31 vertices/axis. Dense grid fits in LDS as half2.
#define R0 31
#define DENSE0_N (R0 * R0 * R0)        // 29791
#define DENSE0_BYTES (DENSE0_N * 4)    // 119164 B < 160 KiB

// native vector types usable with __builtin_nontemporal_*
typedef float v4f __attribute__((ext_vector_type(4)));

__device__ __forceinline__ uint32_t hash3(uint32_t ix, uint32_t iy, uint32_t iz) {
    return (ix ^ (iy * 11614769u) ^ (iz * 2654435761u)) & HASHMAP_MASK;
}

__device__ __forceinline__ float2 h2f(uint32_t p) {
    return __half22float2(*(const __half2*)&p);
}
__device__ __forceinline__ uint32_t f2h(float a, float b) {
    const __half2 p = __floats2half2_rn(a, b);
    return *(const uint32_t*)&p;
}

// ---------------- fp32 path (fallback only) ----------------
__device__ __forceinline__ float2 level_embed_p(float px, float py, float pz,
                                                const float* __restrict__ tables,
                                                int li, float r)
{
    const uint32_t P1 = 11614769u;
    const uint32_t P2 = 2654435761u;

    const float sx = px * r, sy = py * r, sz = pz * r;
    const float bx = floorf(sx), by = floorf(sy), bz = floorf(sz);
    const float tx = sx - bx, ty = sy - by, tz = sz - bz;
    const float ux = 1.0f - tx, uy = 1.0f - ty, uz = 1.0f - tz;

    const uint32_t ix = (uint32_t)(int)bx;
    const uint32_t iy = (uint32_t)(int)by;
    const uint32_t iz = (uint32_t)(int)bz;

    const uint32_t hy0 = iy * P1, hy1 = (iy + 1u) * P1;
    const uint32_t hz0 = iz * P2, hz1 = (iz + 1u) * P2;

    uint32_t S[4];
    float W[4];
    S[0] = hy0 ^ hz0;  W[0] = uy * uz;
    S[1] = hy0 ^ hz1;  W[1] = uy * tz;
    S[2] = hy1 ^ hz0;  W[2] = ty * uz;
    S[3] = hy1 ^ hz1;  W[3] = ty * tz;

    const float* tab = tables + (size_t)li * HASHMAP_SIZE * 2;
    const float2* __restrict__ tab2 = (const float2*)tab;

    float f0 = 0.0f, f1 = 0.0f;
    #pragma unroll
    for (int c = 0; c < 4; ++c) {
        const uint32_t h0 = (ix ^ S[c]) & HASHMAP_MASK;
        const uint32_t h1 = ((ix + 1u) ^ S[c]) & HASHMAP_MASK;
        const float2 e0 = tab2[h0];
        const float2 e1 = tab2[h1];
        f0 += W[c] * (ux * e0.x + tx * e1.x);
        f1 += W[c] * (ux * e0.y + tx * e1.y);
    }
    return make_float2(f0, f1);
}

// ---------------- fp16 hash gather, XOR-block paired ----------------
// h(x-corner pair) differ by D = ix^(ix+1): D==1 -> same aligned 8B pair
// (1 load); D==3 -> same aligned 16B 4-entry block (1 uint4 load); else
// 2 scalar loads. Avg 1.25 transactions per (y,z) combo = 5 per point-level.
__device__ __forceinline__ float2 level_embed_h16(float px, float py, float pz,
                                                  const uint32_t* __restrict__ t16,
                                                  float r)
{
    const uint32_t P1 = 11614769u;
    const uint32_t P2 = 2654435761u;

    const float sx = px * r, sy = py * r, sz = pz * r;
    const float bx = floorf(sx), by = floorf(sy), bz = floorf(sz);
    const float tx = sx - bx, ty = sy - by, tz = sz - bz;
    const float ux = 1.0f - tx, uy = 1.0f - ty, uz = 1.0f - tz;

    const uint32_t ix = (uint32_t)(int)bx;
    const uint32_t iy = (uint32_t)(int)by;
    const uint32_t iz = (uint32_t)(int)bz;

    const uint32_t hy0 = iy * P1, hy1 = (iy + 1u) * P1;
    const uint32_t hz0 = iz * P2, hz1 = (iz + 1u) * P2;

    uint32_t S[4];
    float W[4];
    S[0] = hy0 ^ hz0;  W[0] = uy * uz;
    S[1] = hy0 ^ hz1;  W[1] = uy * tz;
    S[2] = hy1 ^ hz0;  W[2] = ty * uz;
    S[3] = hy1 ^ hz1;  W[3] = ty * tz;

    const uint32_t D = ix ^ (ix + 1u);   // 1, 3, 7, 15, ...

    float f0 = 0.0f, f1 = 0.0f;
    if (D == 1u) {
        // corners {h0, h0^1} in one aligned 8B pair
        #pragma unroll
        for (int c = 0; c < 4; ++c) {
            const uint32_t h0 = (ix ^ S[c]) & HASHMAP_MASK;
            const uint2 v = ((const uint2*)t16)[h0 >> 1];
            const uint32_t p0 = (h0 & 1u) ? v.y : v.x;
            const uint32_t p1 = (h0 & 1u) ? v.x : v.y;
            const float2 e0 = h2f(p0);
            const float2 e1 = h2f(p1);
            f0 += W[c] * (ux * e0.x + tx * e1.x);
            f1 += W[c] * (ux * e0.y + tx * e1.y);
        }
    } else if (D == 3u) {
        // corners {h0, h0^3} in one aligned 16B 4-entry block
        #pragma unroll
        for (int c = 0; c < 4; ++c) {
            const uint32_t h0 = (ix ^ S[c]) & HASHMAP_MASK;
            const uint32_t b = h0 & ~3u;
            const uint4 v = *(const uint4*)(t16 + b);
            const uint32_t i0 = h0 & 3u;                 // corner1 index = 3 - i0
            // p0 = v[i0]
            const uint32_t s01 = (i0 & 1u) ? v.y : v.x;
            const uint32_t s23 = (i0 & 1u) ? v.w : v.z;
            const uint32_t p0  = (i0 & 2u) ? s23 : s01;
            // p1 = v[3 - i0]
            const uint32_t r01 = (i0 & 1u) ? v.z : v.w;  // i0 in {0,1} -> {3,2}
            const uint32_t r23 = (i0 & 1u) ? v.x : v.y;  // i0 in {2,3} -> {1,0}
            const uint32_t p1  = (i0 & 2u) ? r23 : r01;
            const float2 e0 = h2f(p0);
            const float2 e1 = h2f(p1);
            f0 += W[c] * (ux * e0.x + tx * e1.x);
            f1 += W[c] * (ux * e0.y + tx * e1.y);
        }
    } else {
        #pragma unroll
        for (int c = 0; c < 4; ++c) {
            const uint32_t h0 = (ix ^ S[c]) & HASHMAP_MASK;
            const uint32_t h1 = h0 ^ D;    // D < 2^10, within mask
            const float2 e0 = h2f(t16[h0]);
            const float2 e1 = h2f(t16[h1]);
            f0 += W[c] * (ux * e0.x + tx * e1.x);
            f1 += W[c] * (ux * e0.y + tx * e1.y);
        }
    }
    return make_float2(f0, f1);
}

// ---------------- setup kernels ----------------
// Pack levels 1..3 tables to fp16 (half2 per entry).
__global__ __launch_bounds__(256) void convert_fp16(
    const float* __restrict__ tables, uint32_t* __restrict__ t16)
{
    const int i = blockIdx.x * blockDim.x + threadIdx.x;
    if (i >= 3 * (int)HASHMAP_SIZE) return;
    const float2 e = ((const float2*)tables)[HASHMAP_SIZE + i];  // levels 1..3
    t16[i] = f2h(e.x, e.y);
}

// Level-0 dense vertex grid as half2 (for LDS staging in final).
__global__ __launch_bounds__(256) void build_dense0(
    const float* __restrict__ tables, uint32_t* __restrict__ dense0)
{
    const int v = blockIdx.x * blockDim.x + threadIdx.x;
    if (v >= DENSE0_N) return;
    const int vx = v / (R0 * R0);
    const int rem = v - vx * (R0 * R0);
    const int vy = rem / R0;
    const int vz = rem - vy * R0;
    const uint32_t h = hash3((uint32_t)vx, (uint32_t)vy, (uint32_t)vz);
    const float2 e = ((const float2*)tables)[h];   // level-0 table at offset 0
    dense0[v] = f2h(e.x, e.y);
}

// ---------------- pass kernels ----------------
// Levels 1,2: one fp16 table (2 MB, L2-resident) per launch.
__global__ __launch_bounds__(256) void pass_hash(
    const float* __restrict__ x, const uint32_t* __restrict__ t16,
    uint32_t* __restrict__ ws, float r, int n)
{
    const int i = blockIdx.x * blockDim.x + threadIdx.x;
    if (i >= n) return;
    const float px = __builtin_nontemporal_load(x + 3 * (size_t)i + 0);
    const float py = __builtin_nontemporal_load(x + 3 * (size_t)i + 1);
    const float pz = __builtin_nontemporal_load(x + 3 * (size_t)i + 2);
    const float2 e = level_embed_h16(px, py, pz, t16, r);
    __builtin_nontemporal_store(f2h(e.x, e.y), ws + i);
}

extern __shared__ uint32_t s_dense[];   // DENSE0_N packed half2

// Final: level 3 (fp16 hash gather) + level 0 (LDS) + combine ws1/ws2.
__global__ __launch_bounds__(1024) void final16_kernel(
    const float* __restrict__ x, const uint32_t* __restrict__ t16_l3,
    const uint32_t* __restrict__ dense0,
    const uint32_t* __restrict__ ws1, const uint32_t* __restrict__ ws2,
    float* __restrict__ out, int n)
{
    for (int i = threadIdx.x; i < DENSE0_N; i += 1024)
        s_dense[i] = dense0[i];
    __syncthreads();

    const size_t stride = (size_t)gridDim.x * 1024;
    for (size_t i = (size_t)blockIdx.x * 1024 + threadIdx.x; i < (size_t)n; i += stride) {
        const float px = __builtin_nontemporal_load(x + 3 * i + 0);
        const float py = __builtin_nontemporal_load(x + 3 * i + 1);
        const float pz = __builtin_nontemporal_load(x + 3 * i + 2);

        // level 3: global fp16 gathers (long latency; issue first)
        const float2 e3 = level_embed_h16(px, py, pz, t16_l3, 512.0f);

        // level 0 from LDS dense grid
        const float sx = px * 30.0f, sy = py * 30.0f, sz = pz * 30.0f;
        const float bx = floorf(sx), by = floorf(sy), bz = floorf(sz);
        const float tx = sx - bx, ty = sy - by, tz = sz - bz;
        const float uxv = 1.0f - tx, uyv = 1.0f - ty, uzv = 1.0f - tz;
        const int ix = (int)bx, iy = (int)by, iz = (int)bz;
        const int lin = (ix * R0 + iy) * R0 + iz;

        float f0 = 0.0f, f1 = 0.0f;
        #pragma unroll
        for (int dx = 0; dx < 2; ++dx) {
            const float wx = dx ? tx : uxv;
            #pragma unroll
            for (int dy = 0; dy < 2; ++dy) {
                const float wxy = wx * (dy ? ty : uyv);
                const int base = lin + (dx * R0 + dy) * R0;   // z-corners adjacent
                const float2 c0 = h2f(s_dense[base]);
                const float2 c1 = h2f(s_dense[base + 1]);
                f0 += wxy * (uzv * c0.x + tz * c1.x);
                f1 += wxy * (uzv * c0.y + tz * c1.y);
            }
        }

        const float2 e1 = h2f(__builtin_nontemporal_load(ws1 + i));
        const float2 e2 = h2f(__builtin_nontemporal_load(ws2 + i));

        v4f* op = (v4f*)(out + 8 * i);
        v4f lo = {f0, f1, e1.x, e1.y};
        v4f hi = {e2.x, e2.y, e3.x, e3.y};
        __builtin_nontemporal_store(lo, op);
        __builtin_nontemporal_store(hi, op + 1);
    }
}

// Fallback (ws too small / attribute failure): fp32 per-level pass into out.
__global__ __launch_bounds__(256) void pass_direct_kernel(
    const float* __restrict__ x, const float* __restrict__ tables,
    float* __restrict__ out, int li, float r, int n)
{
    const int i = blockIdx.x * blockDim.x + threadIdx.x;
    if (i >= n) return;
    const float px = x[3 * (size_t)i + 0];
    const float py = x[3 * (size_t)i + 1];
    const float pz = x[3 * (size_t)i + 2];
    const float2 e = level_embed_p(px, py, pz, tables, li, r);
    float2* op = (float2*)(out + 8 * (size_t)i + 2 * li);
    *op = e;
}

extern "C" void kernel_launch(void* const* d_in, const int* in_sizes, int n_in,
                              void* d_out, int out_size, void* d_ws, size_t ws_size,
                              hipStream_t stream) {
    const float* x = (const float*)d_in[0];        // [N, 3]
    const float* tables = (const float*)d_in[1];   // [4, 2^19, 2]
    float* out = (float*)d_out;                    // [N, 8]
    const int n = in_sizes[0] / 3;

    // ws layout (bytes):
    //   [0, 6MB)        : t16 for levels 1,2,3 (2 MB each)
    //   [+DENSE0_BYTES) : level-0 dense grid
    //   [+4n)           : ws1 (half2[n])
    //   [+4n)           : ws2 (half2[n])
    const size_t t16_bytes = 3 * (size_t)HASHMAP_SIZE * 4;
    const size_t off_d0    = t16_bytes;
    const size_t off_ws1   = off_d0 + DENSE0_BYTES;
    const size_t off_ws2   = off_ws1 + (size_t)n * 4;
    const size_t ws_needed = off_ws2 + (size_t)n * 4;

    bool fused_ok = (ws_size >= ws_needed);
    if (fused_ok) {
        static int attr_ok = -1;
        if (attr_ok < 0) {
            attr_ok = (hipFuncSetAttribute(
                           reinterpret_cast<const void*>(final16_kernel),
                           hipFuncAttributeMaxDynamicSharedMemorySize,
                           DENSE0_BYTES) == hipSuccess) ? 1 : 0;
        }
        fused_ok = (attr_ok == 1);
    }

    if (fused_ok) {
        char* wsb = (char*)d_ws;
        uint32_t* t16    = (uint32_t*)wsb;
        uint32_t* dense0 = (uint32_t*)(wsb + off_d0);
        uint32_t* ws1    = (uint32_t*)(wsb + off_ws1);
        uint32_t* ws2    = (uint32_t*)(wsb + off_ws2);

        convert_fp16<<<(3 * HASHMAP_SIZE + 255) / 256, 256, 0, stream>>>(tables, t16);
        build_dense0<<<(DENSE0_N + 255) / 256, 256, 0, stream>>>(tables, dense0);

        const int block = 256;
        const int grid = (n + block - 1) / block;
        pass_hash<<<grid, block, 0, stream>>>(x, t16, ws1, 80.0f, n);
        pass_hash<<<grid, block, 0, stream>>>(x, t16 + HASHMAP_SIZE, ws2, 210.0f, n);
        final16_kernel<<<256, 1024, DENSE0_BYTES, stream>>>(
            x, t16 + 2 * HASHMAP_SIZE, dense0, ws1, ws2, out, n);
    } else {
        const float res[N_LEVELS] = {30.0f, 80.0f, 210.0f, 512.0f};
        const int block = 256;
        const int grid = (n + block - 1) / block;
        for (int li = 0; li < N_LEVELS; ++li) {
            pass_direct_kernel<<<grid, block, 0, stream>>>(
                x, tables, out, li, res[li], n);
        }
    }
}